// Round 11
// baseline (407.818 us; speedup 1.0000x reference)
//
#include <hip/hip_runtime.h>
#include <math.h>

#define D_MODEL 256
#define N_EXP   16
#define N_VIEWS 3
#define N_TOK   8192
#define TOPK    4
#define HDIM    1024
#define CH      64
#define NCH     16
#define NSUB    32             // 32-col K sub-chunks of HDIM for the ffn pipeline
#define ROWS    128            // rows per ffn tile (v20: 2x, amortizes B-frag LDS reads)
#define TI_MAX  20             // tiles per group: covers L <= 2560 (measured ~2048±44)
#define NGROUP  48
#define GCAP    8192           // fixed capacity per (view,expert) group
#define REC_ELTS 32768         // chunk record: W1 half (16384) + W2 half (16384) shorts

typedef short s16x8 __attribute__((ext_vector_type(8)));
typedef float f32x4 __attribute__((ext_vector_type(4)));

__device__ __forceinline__ unsigned short f2bf(float x) {
    union { float f; unsigned u; } a; a.f = x;
    unsigned r = a.u + 0x7FFFu + ((a.u >> 16) & 1u);   // RNE
    return (unsigned short)(r >> 16);
}

// async global -> LDS, 16 B per lane; LDS dst is wave-uniform base + lane*16
__device__ __forceinline__ void dma16(const unsigned short* gp, unsigned short* lp) {
    __builtin_amdgcn_global_load_lds(
        (const __attribute__((address_space(1))) unsigned int*)gp,
        (__attribute__((address_space(3))) unsigned int*)lp, 16, 0, 0);
}

// stage one 16 KB W1 sub-chunk (sc = 0..31): record c = sc>>1, half h = sc&1.
// 8 waves x 2 dma16 x 1KB. LDS run ks -> ldst[ks*1024 .. +1024).
__device__ __forceinline__ void dma_sub(const unsigned short* wrec0, int sc,
                                        unsigned short* ldst, int wave, int lane) {
    const unsigned short* g = wrec0 + (size_t)(sc >> 1) * REC_ELTS
                                    + (size_t)((wave * 4 + (sc & 1) * 2) * 512);
    dma16(g + lane * 8,       ldst + wave * 1024);
    dma16(g + 512 + lane * 8, ldst + wave * 1024 + 512);
}

// ------------------------------------------------------------------
// merged prep (byte-identical to the r10 passing build).
// ------------------------------------------------------------------
#define T1_STRIDE 65    // 256 x 65 f32 = 66560 B
#define T2_STRIDE 257   // 64 x 257 f32 = 65792 B

__global__ __launch_bounds__(256) void prep_kernel(
    const float* __restrict__ v0, const float* __restrict__ v1, const float* __restrict__ v2,
    const float* __restrict__ rw, const float* __restrict__ keys,
    const float* __restrict__ W1, const float* __restrict__ W2,
    unsigned short* __restrict__ Wf, unsigned short* __restrict__ Xbf,
    int* __restrict__ counts, int* __restrict__ rowTok, float* __restrict__ rowGate)
{
    __shared__ __align__(16) char smem[66560];   // union: wfrag T1 / route arrays

    int bid = blockIdx.x;
    int tid = threadIdx.x;
    int sept = bid / 7, r7 = bid % 7;            // 896 = 128 * 7

    if (r7 < 4) {
        // ================= wfrag role (512 blocks) =================
        int wb = sept * 4 + r7;                  // 0..511
        int c = wb & 15, e = (wb >> 4) & 15, z = wb >> 8;
        unsigned short* dst = Wf + (size_t)(e * NCH + c) * REC_ELTS;
        if (z == 0) {
            float* T1 = (float*)smem;
            const float* src = W1 + (size_t)e * 256 * 1024 + c * 64;
            #pragma unroll
            for (int p = 0; p < 16; p++) {
                int k = p * 16 + (tid >> 4), c4 = (tid & 15) * 4;
                float4 v = *(const float4*)(src + (size_t)k * 1024 + c4);
                T1[k * T1_STRIDE + c4]     = v.x;
                T1[k * T1_STRIDE + c4 + 1] = v.y;
                T1[k * T1_STRIDE + c4 + 2] = v.z;
                T1[k * T1_STRIDE + c4 + 3] = v.w;
            }
            __syncthreads();
            #pragma unroll
            for (int i = 0; i < 8; i++) {
                int idx = tid + i * 256;
                int lane = idx & 63, nt = (idx >> 6) & 3, ks = idx >> 8;
                int nl = nt * 16 + (lane & 15);
                int kbase = ks * 32 + (lane >> 4) * 8;
                s16x8 o;
                #pragma unroll
                for (int j = 0; j < 8; j++) o[j] = (short)f2bf(T1[(kbase + j) * T1_STRIDE + nl]);
                *(s16x8*)(dst + (size_t)idx * 8) = o;
            }
        } else {
            float* T2 = (float*)smem;
            const float* src = W2 + ((size_t)e * 1024 + c * 64) * 256;
            #pragma unroll
            for (int p = 0; p < 16; p++) {
                int k2l = p * 4 + (tid >> 6), c4 = (tid & 63) * 4;
                float4 v = *(const float4*)(src + (size_t)k2l * 256 + c4);
                T2[k2l * T2_STRIDE + c4]     = v.x;
                T2[k2l * T2_STRIDE + c4 + 1] = v.y;
                T2[k2l * T2_STRIDE + c4 + 2] = v.z;
                T2[k2l * T2_STRIDE + c4 + 3] = v.w;
            }
            __syncthreads();
            dst += 16384;
            #pragma unroll
            for (int i = 0; i < 8; i++) {
                int idx = tid + i * 256;
                int lane = idx & 63, ntile = (idx >> 6) & 15, ks2 = idx >> 10;
                int n = ntile * 16 + (lane & 15);
                int kbase = ks2 * 32 + (lane >> 4) * 8;
                s16x8 o;
                #pragma unroll
                for (int j = 0; j < 8; j++) o[j] = (short)f2bf(T2[(kbase + j) * T2_STRIDE + n]);
                *(s16x8*)(dst + (size_t)idx * 8) = o;
            }
        }
        return;
    }

    // ================= route role (384 blocks) =================
    int rb = sept * 3 + (r7 - 4);                // 0..383
    float* XsT    = (float*)smem;                // 32 KB: [128 dims][64 tok]
    float* cwS    = (float*)(smem + 32768);      // 16 KB
    float* logitS = (float*)(smem + 49152);      // 4352 B (64 x 17)
    float* knS    = (float*)(smem + 53504);      // 64 B
    int*   lcnt   = (int*)(smem + 53568);
    int*   lbase  = (int*)(smem + 53632);
    int*   fpos   = (int*)(smem + 53696);
    int*   eIdx   = (int*)(smem + 53760);        // 1 KB
    float* gV     = (float*)(smem + 54784);      // 1 KB -> total 55808 B

    int view = rb >> 7, xb = rb & 127;
    const float* src = view == 0 ? v0 : (view == 1 ? v1 : v2);

    // cw = rw + 2*keys; knS = |key|^2; counters = 0
    for (int i = tid; i < N_EXP * D_MODEL; i += 256)
        cwS[i] = rw[view * N_EXP * D_MODEL + i] + 2.0f * keys[i];
    if (tid < N_EXP) {
        const float4* kp = (const float4*)(keys + tid * D_MODEL);
        float s = 0.f;
        for (int d = 0; d < 64; d++) { float4 k = kp[d]; s += k.x*k.x + k.y*k.y + k.z*k.z + k.w*k.w; }
        knS[tid] = s; lcnt[tid] = 0; fpos[tid] = 0;
    }

    int wave = tid >> 6, lane = tid & 63;
    float a0 = 0.f, a1 = 0.f, a2 = 0.f, a3 = 0.f;   // persist across both passes

    // ---- 2-pass: stage 128 dims col-major + partial dot (exact f32)
    #pragma unroll 1
    for (int p = 0; p < 2; p++) {
        {
            int t = tid >> 2, q = tid & 3;        // token-local, 32-dim strip
            int token = xb * 64 + t;
            const float4* vp = (const float4*)(src + (size_t)token * D_MODEL + p * 128 + q * 32);
            ushort4* xo = (ushort4*)(Xbf + ((size_t)view * N_TOK + token) * D_MODEL + p * 128 + q * 32);
            #pragma unroll
            for (int i = 0; i < 8; i++) {
                float4 v = vp[i];
                ushort4 h; h.x = f2bf(v.x); h.y = f2bf(v.y); h.z = f2bf(v.z); h.w = f2bf(v.w);
                xo[i] = h;
                int d = q * 32 + i * 4;
                XsT[(d + 0) * 64 + t] = v.x;
                XsT[(d + 1) * 64 + t] = v.y;
                XsT[(d + 2) * 64 + t] = v.z;
                XsT[(d + 3) * 64 + t] = v.w;
            }
        }
        __syncthreads();
        {
            const float* xcol = &XsT[lane];
            const float* c0 = &cwS[(wave * 4 + 0) * D_MODEL + p * 128];
            const float* c1 = &cwS[(wave * 4 + 1) * D_MODEL + p * 128];
            const float* c2 = &cwS[(wave * 4 + 2) * D_MODEL + p * 128];
            const float* c3 = &cwS[(wave * 4 + 3) * D_MODEL + p * 128];
            #pragma unroll 4
            for (int d4 = 0; d4 < 32; d4++) {
                float x0 = xcol[(d4 * 4 + 0) * 64];
                float x1 = xcol[(d4 * 4 + 1) * 64];
                float x2 = xcol[(d4 * 4 + 2) * 64];
                float x3 = xcol[(d4 * 4 + 3) * 64];
                float4 w0 = *(const float4*)(c0 + d4 * 4);
                float4 w1 = *(const float4*)(c1 + d4 * 4);
                float4 w2 = *(const float4*)(c2 + d4 * 4);
                float4 w3 = *(const float4*)(c3 + d4 * 4);
                a0 += x0 * w0.x + x1 * w0.y + x2 * w0.z + x3 * w0.w;
                a1 += x0 * w1.x + x1 * w1.y + x2 * w1.z + x3 * w1.w;
                a2 += x0 * w2.x + x1 * w2.y + x2 * w2.z + x3 * w2.w;
                a3 += x0 * w3.x + x1 * w3.y + x2 * w3.z + x3 * w3.w;
            }
        }
        __syncthreads();   // WAR: XsT re-staged next pass
    }
    logitS[lane * 17 + wave * 4 + 0] = a0 - knS[wave * 4 + 0];
    logitS[lane * 17 + wave * 4 + 1] = a1 - knS[wave * 4 + 1];
    logitS[lane * 17 + wave * 4 + 2] = a2 - knS[wave * 4 + 2];
    logitS[lane * 17 + wave * 4 + 3] = a3 - knS[wave * 4 + 3];
    __syncthreads();

    // ---- per-token top-k + softmax (same algorithm / tie-break order)
    if (tid < 64) {
        int tl = tid;
        float lg[N_EXP];
        #pragma unroll
        for (int e = 0; e < N_EXP; e++) lg[e] = logitS[tl * 17 + e];
        int idxs[TOPK]; float vals[TOPK];
        #pragma unroll
        for (int k = 0; k < TOPK; k++) {
            float best = -1e30f; int bi = 0;
            #pragma unroll
            for (int e = 0; e < N_EXP; e++)
                if (lg[e] > best) { best = lg[e]; bi = e; }
            idxs[k] = bi; vals[k] = best;
            #pragma unroll
            for (int e = 0; e < N_EXP; e++)
                lg[e] = (e == bi) ? -1e30f : lg[e];
        }
        float m = vals[0], s = 0.f, ex[TOPK];
        #pragma unroll
        for (int k = 0; k < TOPK; k++) { ex[k] = __expf(vals[k] - m); s += ex[k]; }
        float inv = 1.0f / s;
        #pragma unroll
        for (int k = 0; k < TOPK; k++) {
            eIdx[tl * 4 + k] = idxs[k];
            gV[tl * 4 + k]   = ex[k] * inv;
            atomicAdd(&lcnt[idxs[k]], 1);
        }
    }
    __syncthreads();
    if (tid < N_EXP)
        lbase[tid] = lcnt[tid] ? atomicAdd(&counts[view * N_EXP + tid], lcnt[tid]) : 0;
    __syncthreads();
    // ---- parallel fill (order within group arbitrary; ffn order-independent)
    {
        int e  = eIdx[tid];
        float gv = gV[tid];
        int pos = atomicAdd(&fpos[e], 1);
        int dst = (view * N_EXP + e) * GCAP + lbase[e] + pos;
        rowTok[dst]  = xb * 64 + (tid >> 2);
        rowGate[dst] = gv;
    }
}

// ------------------------------------------------------------------
// fused FFN v20: LDS-pipe diet. v12 phase budget: 16 waves x 18 b128 +
// 8 b16 = ~4200 of 5300 cyc/phase on the per-CU LDS pipe (80% busy) —
// THE limiter (explains v13/v15 nulls: occupancy/VALU weren't binding).
//  - ROWS=128, wave = (mt: 32 rows) x (nh: 16 cols): each W1 B-frag read
//    feeds 2 MFMAs (2 m-subtiles) -> GEMM1 LDS reads HALVED per MFMA.
//    Per CU/phase: 8 waves x (10 b128 + 8 b16) = ~1350 cyc LDS ~= 1240
//    MFMA -> pipes balanced.
//  - GEMM2: per wave 2 m-tiles x 8 n-tiles (full 256 out cols per nh
//    half), w2r[8] direct from L2 as before. acc2 = 64 VGPR.
//  - ~200 VGPR -> 1 block/CU (launch_bounds(512,2)); LDS 80 KB.
//  - Same depth-3 counted-vmcnt chassis; boundary = vmcnt(13)
//    (DMA(cc+2)x2 + b1 + w2r x8 + DMA(cc+3)x2). Boundary 0 retires
//    DMA(1) (15 outstanding -> 13). GEMM2's w2r wait (vmcnt(3)) retires
//    DMA(cc+1) mid-phase; barrier globalizes. No in-loop drains.
// STATIC schedule: xcd = blockIdx&7 owns experts {2x,2x+1} x 3 views.
// ------------------------------------------------------------------
__global__ __launch_bounds__(512, 2) void ffn_kernel(
    const unsigned short* __restrict__ Xbf, const unsigned short* __restrict__ Wf,
    const float* __restrict__ b1, const float* __restrict__ b2,
    const int* __restrict__ counts, const int* __restrict__ rowTok,
    const float* __restrict__ rowGate, float* __restrict__ out)
{
    __shared__ __align__(16) unsigned short W1buf[4][8192];   // 64 KB quad buffer
    __shared__ __align__(16) unsigned short Hc[2][4096];      // 16 KB dbuf, A-frag order

    int s = blockIdx.x;
    int xcd = s & 7, k = s >> 3;
    int j = k % 6, ti = k / 6;                 // j: group-of-xcd, ti: tile 0..TI_MAX-1
    int e = 2 * xcd + (j & 1), view = j >> 1;
    int g = view * N_EXP + e;
    int L = counts[g];
    int r0 = ti * ROWS;
    if (r0 >= L) return;                       // block-uniform: safe before barriers
    int base = g * GCAP;

    int tid = threadIdx.x;
    int wave = tid >> 6, lane = tid & 63, lmod = lane & 15, quad = lane >> 4;

    const unsigned short* wchunk = Wf + (size_t)e * NCH * REC_ELTS;

    int mt = wave & 3, nh = wave >> 2;           // mt: 32-row group; nh: 16-col (G1) / 128-col (G2)

    // X A-fragments for 32 rows (64 VGPR); tok direct from global.
    s16x8 areg[2][8];
    #pragma unroll
    for (int m = 0; m < 2; m++) {
        int gr = r0 + mt * 32 + m * 16 + lmod;
        int token = (gr < L) ? rowTok[base + gr] : 0;
        const unsigned short* xp = Xbf + ((size_t)view * N_TOK + token) * D_MODEL;
        #pragma unroll
        for (int ks = 0; ks < 8; ks++)
            areg[m][ks] = *(const s16x8*)(xp + ks * 32 + quad * 8);
    }
    float bbCur = b1[e * HDIM + nh * 16 + lmod];   // sub-0 bias (older than all DMAs)

    f32x4 acc2[2][8];
    #pragma unroll
    for (int m = 0; m < 2; m++)
        #pragma unroll
        for (int nt = 0; nt < 8; nt++) acc2[m][nt] = (f32x4){0.f, 0.f, 0.f, 0.f};

    // ---- prologue: each DMA pinned in its own region -> issue order certain.
    __builtin_amdgcn_sched_barrier(0);
    dma_sub(wchunk, 0, &W1buf[0][0], wave, lane);
    __builtin_amdgcn_sched_barrier(0);
    dma_sub(wchunk, 1, &W1buf[1][0], wave, lane);
    __builtin_amdgcn_sched_barrier(0);
    dma_sub(wchunk, 2, &W1buf[2][0], wave, lane);
    __builtin_amdgcn_sched_barrier(0);
    asm volatile("s_waitcnt vmcnt(4)" ::: "memory");   // retire DMA(0); keep DMA(1),(2)
    __builtin_amdgcn_sched_barrier(0);
    __builtin_amdgcn_s_barrier();                  // buf0 valid for all waves
    __builtin_amdgcn_sched_barrier(0);

    s16x8 w2r[8] = {};

    #pragma unroll 1
    for (int cc = 0; cc < NSUB; cc++) {
        // b1 prefetch for phase cc+1 (FIFO anchor; clamped at tail)
        int bn = (cc + 1 < NSUB) ? cc + 1 : NSUB - 1;
        float bbNext = b1[e * HDIM + bn * 32 + nh * 16 + lmod];

        // GEMM1(cc): 32 rows x 16 cols per wave, K=256; each B-frag read
        // feeds BOTH m-subtiles (LDS-read amortization — the v20 point)
        const unsigned short* w1s = &W1buf[cc & 3][0];
        f32x4 a1[2];
        a1[0] = (f32x4){0.f, 0.f, 0.f, 0.f};
        a1[1] = (f32x4){0.f, 0.f, 0.f, 0.f};
        __builtin_amdgcn_s_setprio(1);
        #pragma unroll
        for (int ks = 0; ks < 8; ks++) {
            s16x8 bw = *(const s16x8*)(w1s + ks * 1024 + nh * 512 + lane * 8);
            a1[0] = __builtin_amdgcn_mfma_f32_16x16x32_bf16(areg[0][ks], bw, a1[0], 0, 0, 0);
            a1[1] = __builtin_amdgcn_mfma_f32_16x16x32_bf16(areg[1][ks], bw, a1[1], 0, 0, 0);
        }
        __builtin_amdgcn_s_setprio(0);

        // bias + gelu -> Hc[cc&1] (A-frag order; same formula as v12 per m)
        {
            unsigned short* hd = &Hc[cc & 1][0];
            #pragma unroll
            for (int m = 0; m < 2; m++) {
                int bo = (mt * 2 + m) * 512 + (nh * 2 + (lmod >> 3)) * 128 + quad * 32 + (lmod & 7);
                #pragma unroll
                for (int r = 0; r < 4; r++) {
                    float h = a1[m][r] + bbCur;
                    float u = h * (0.7978845608f + 0.0356774081f * h * h);
                    float ex2 = __expf(2.f * u);
                    float tn = 1.f - 2.f * __builtin_amdgcn_rcpf(1.f + ex2);
                    hd[bo + r * 8] = f2bf(0.5f * h * (1.f + tn));
                }
            }
        }

        // GEMM2(cc-1): 32 rows x 128 cols per wave, K=32 (consumes w2r(cc-1);
        // the compiler's wait here retires DMA(cc+1) per-wave -> with the
        // barrier below this is the W1-freshness chain)
        if (cc > 0) {
            const unsigned short* hs = &Hc[(cc - 1) & 1][0];
            s16x8 afr[2];
            #pragma unroll
            for (int m = 0; m < 2; m++)
                afr[m] = *(const s16x8*)(hs + ((mt * 2 + m) * 64 + lane) * 8);
            __builtin_amdgcn_s_setprio(1);
            #pragma unroll
            for (int nt = 0; nt < 8; nt++)
                #pragma unroll
                for (int m = 0; m < 2; m++)
                    acc2[m][nt] = __builtin_amdgcn_mfma_f32_16x16x32_bf16(
                        afr[m], w2r[nt], acc2[m][nt], 0, 0, 0);
            __builtin_amdgcn_s_setprio(0);
        }

        // reload w2r with sub cc's W2 B-frags: cols nh*128..+128, k = the
        // sub's 32 (ks2 = cc&1). Direct from global/L2; consumed next phase.
        {
            const unsigned short* w2p = wchunk + (size_t)(cc >> 1) * REC_ELTS + 16384;
            #pragma unroll
            for (int nt = 0; nt < 8; nt++)
                w2r[nt] = *(const s16x8*)(w2p
                    + (size_t)((((cc & 1) * 16 + nh * 8 + nt) * 64 + lane)) * 8);
        }

        // ---- DMA region: pinned, provably the newest VMEM ops ----
        __builtin_amdgcn_sched_barrier(0);
        if (cc + 3 < NSUB)
            dma_sub(wchunk, cc + 3, &W1buf[(cc + 3) & 3][0], wave, lane);
        __builtin_amdgcn_sched_barrier(0);

        bbCur = bbNext;

        // ---- phase boundary: counted wait (no drain) + barrier.
        // steady outstanding: DMA(cc+2)x2 + b1 x1 + w2r x8 + DMA(cc+3)x2 = 13.
        // boundary 0: 15 outstanding -> retires DMA(1)x2 (load-bearing).
        asm volatile("s_waitcnt vmcnt(13) lgkmcnt(0)" ::: "memory");
        __builtin_amdgcn_sched_barrier(0);
        __builtin_amdgcn_s_barrier();
        __builtin_amdgcn_sched_barrier(0);
    }

    // drain everything (incl. any LDS-DMA) BEFORE kernel end
    asm volatile("s_waitcnt vmcnt(0)" ::: "memory");

    // ---- peeled GEMM2 for sub 31 (Hc published by the final barrier)
    {
        const unsigned short* hs = &Hc[(NSUB - 1) & 1][0];
        s16x8 afr[2];
        #pragma unroll
        for (int m = 0; m < 2; m++)
            afr[m] = *(const s16x8*)(hs + ((mt * 2 + m) * 64 + lane) * 8);
        #pragma unroll
        for (int nt = 0; nt < 8; nt++)
            #pragma unroll
            for (int m = 0; m < 2; m++)
                acc2[m][nt] = __builtin_amdgcn_mfma_f32_16x16x32_bf16(
                    afr[m], w2r[nt], acc2[m][nt], 0, 0, 0);
    }

    // epilogue: out[token] += gate * (acc2 + b2); tok/gate direct from global
    int   tokR[2][4];
    float gateR[2][4];
    #pragma unroll
    for (int m = 0; m < 2; m++)
        #pragma unroll
        for (int r = 0; r < 4; r++) {
            int gr = r0 + mt * 32 + m * 16 + quad * 4 + r;
            bool ok = gr < L;
            tokR[m][r]  = ok ? rowTok[base + gr] : -1;
            gateR[m][r] = ok ? rowGate[base + gr] : 0.f;
        }
    #pragma unroll
    for (int nt = 0; nt < 8; nt++) {
        int col = nh * 128 + nt * 16 + lmod;
        float b2v = b2[e * D_MODEL + col];
        #pragma unroll
        for (int m = 0; m < 2; m++) {
            #pragma unroll
            for (int r = 0; r < 4; r++) {
                if (tokR[m][r] >= 0) {
                    atomicAdd(&out[(size_t)tokR[m][r] * D_MODEL + col],
                              gateR[m][r] * (acc2[m][nt][r] + b2v));
                }
            }
        }
    }
}

// ------------------------------------------------------------------
extern "C" void kernel_launch(void* const* d_in, const int* in_sizes, int n_in,
                              void* d_out, int out_size, void* d_ws, size_t ws_size,
                              hipStream_t stream)
{
    const float* v0   = (const float*)d_in[0];
    const float* v1   = (const float*)d_in[1];
    const float* v2   = (const float*)d_in[2];
    const float* rw   = (const float*)d_in[3];
    const float* keys = (const float*)d_in[4];
    const float* W1   = (const float*)d_in[5];
    const float* b1   = (const float*)d_in[6];
    const float* W2   = (const float*)d_in[7];
    const float* b2   = (const float*)d_in[8];
    float* out = (float*)d_out;

    char* p = (char*)d_ws;
    unsigned short* Xbf = (unsigned short*)p; p += (size_t)N_VIEWS * N_TOK * D_MODEL * 2;
    unsigned short* Wf  = (unsigned short*)p; p += (size_t)N_EXP * NCH * REC_ELTS * 2;
    int*   counts = (int*)p;   p += 256;
    int*   rowTok = (int*)p;   p += (size_t)NGROUP * GCAP * 4;
    float* rowGate= (float*)p; p += (size_t)NGROUP * GCAP * 4;

    hipMemsetAsync(counts, 0, NGROUP * sizeof(int), stream);
    hipMemsetAsync(out, 0, (size_t)out_size * sizeof(float), stream);

    prep_kernel<<<896, 256, 0, stream>>>(v0, v1, v2, rw, keys, W1, W2,
                                         Wf, Xbf, counts, rowTok, rowGate);
    ffn_kernel<<<8 * 6 * TI_MAX, 512, 0, stream>>>(Xbf, Wf, b1, b2, counts,
                                                   rowTok, rowGate, out);
}